// Round 6
// baseline (299.419 us; speedup 1.0000x reference)
//
#include <hip/hip_runtime.h>
#include <hip/hip_bf16.h>
#include <hip/hip_fp16.h>

// ---------------------------------------------------------------------------
// GAT link predictor: 2x GATConv + pair MLP.
// R6: GEMM restructured for scalar-load amortization: 128 rows x 64 cols per
//     block, 2 rows/lane (8 FMA-instr per s_load_dwordx4), K tiled by 32 with
//     LDS [128][33] (conflict-free), 16.9 KB LDS -> 8 blocks/CU.
//     fp16 gather tables (h1, h2, uv), fp32 compute everywhere.
// ---------------------------------------------------------------------------

#define LRELU_SLOPE 0.2f

__device__ inline unsigned pkhalf2(float a, float b) {
    __half2 h = __floats2half2_rn(a, b);
    return *(unsigned*)&h;
}

// ---- weight pre-transpose (so GEMM W reads are wave-uniform -> s_load) ----
__global__ void __launch_bounds__(256) prep_kernel(
    const float* __restrict__ W1, const float* __restrict__ W2,
    const float* __restrict__ Wm1,
    float* __restrict__ W1T, float* __restrict__ W2T, float* __restrict__ Wm1T)
{
    int i = blockIdx.x * 256 + threadIdx.x;
    if (i < 16384) {                       // W1 [128][128] -> W1T [128][128]
        int k = i >> 7, j = i & 127;
        W1T[j * 128 + k] = W1[i];
    } else if (i < 16384 + 8192) {         // W2 [128][64] -> W2T [64][128]
        int t = i - 16384;
        int k = t >> 6, j = t & 63;
        W2T[j * 128 + k] = W2[t];
    } else if (i < 16384 + 8192 + 4096) {  // Wm1 [128][32] -> Wm1T [32][128]
        int t = i - 24576;
        int k = t >> 5, j = t & 31;
        Wm1T[j * 128 + k] = Wm1[t];
    }
}

// ---- CSR build ----
__global__ void __launch_bounds__(256) hist_kernel(
    const int* __restrict__ dst, int E, int N, int* __restrict__ deg)
{
    int i = blockIdx.x * 256 + threadIdx.x;
    if (i >= E + N) return;
    int d = (i < E) ? dst[i] : (i - E);
    atomicAdd(deg + d, 1);
}

// hierarchical scan: per-1024-block inclusive scan + block totals
__global__ void __launch_bounds__(1024) scan1_kernel(
    const int* __restrict__ deg, int* __restrict__ rowp,
    int* __restrict__ btot, int n)
{
    __shared__ int wsum[16];
    int t = threadIdx.x, lane = t & 63, wid = t >> 6;
    int idx = blockIdx.x * 1024 + t;
    int v = (idx < n) ? deg[idx] : 0;
    #pragma unroll
    for (int off = 1; off < 64; off <<= 1) {
        int y = __shfl_up(v, off);
        if (lane >= off) v += y;
    }
    if (lane == 63) wsum[wid] = v;
    __syncthreads();
    if (wid == 0) {
        int s = (lane < 16) ? wsum[lane] : 0;
        #pragma unroll
        for (int off = 1; off < 16; off <<= 1) {
            int y = __shfl_up(s, off);
            if (lane >= off) s += y;
        }
        if (lane < 16) wsum[lane] = s;
    }
    __syncthreads();
    if (wid > 0) v += wsum[wid - 1];
    if (idx < n) rowp[idx + 1] = v;
    if (t == 1023) btot[blockIdx.x] = v;
    if (idx == 0) rowp[0] = 0;
}

__global__ void __launch_bounds__(64) scan2_kernel(int* __restrict__ btot, int nb)
{
    int lane = threadIdx.x;
    int v = (lane < nb) ? btot[lane] : 0;
    #pragma unroll
    for (int off = 1; off < 64; off <<= 1) {
        int y = __shfl_up(v, off);
        if (lane >= off) v += y;
    }
    if (lane < nb) btot[lane] = v;
}

__global__ void __launch_bounds__(1024) scan3_kernel(
    int* __restrict__ rowp, const int* __restrict__ btot, int n)
{
    if (blockIdx.x == 0) return;
    int idx = blockIdx.x * 1024 + threadIdx.x;
    if (idx < n) rowp[idx + 1] += btot[blockIdx.x - 1];
}

__global__ void __launch_bounds__(256) scatter_kernel(
    const int* __restrict__ src, const int* __restrict__ dst, int E, int N,
    const int* __restrict__ rowptr, int* __restrict__ cursor,
    int* __restrict__ csrs)
{
    int i = blockIdx.x * 256 + threadIdx.x;
    if (i >= E + N) return;
    int s, d;
    if (i < E) { s = src[i]; d = dst[i]; } else { s = d = i - E; }
    int pos = rowptr[d] + atomicAdd(cursor + d, 1);
    csrs[pos] = s;
}

// ---- fused GEMM + attention-score epilogue; OUT stored fp16 ----
// Block: 256 threads = 4 waves. Tile: 128 rows x 64 cols; wave = 16 cols;
// lane owns rows {lane, lane+64} -> acc[2][16], 8 FMA-instr per s_load_dwordx4.
// K tiled by 32; X tile in LDS [128][33] (33 => bank = lane mod 32, 2-way free).
__global__ void __launch_bounds__(256) gemm_att_kernel(
    const float* __restrict__ X, const float* __restrict__ WT,
    const float* __restrict__ atts, const float* __restrict__ attd,
    __half* __restrict__ OUT, float* __restrict__ oas, float* __restrict__ oad,
    int N, int ncols, int H, int headShift)
{
    __shared__ float xs[128 * 33];
    int tid = threadIdx.x;
    int rowBase = blockIdx.x * 128;
    int colBase = blockIdx.y * 64;
    int lane = tid & 63;
    int wv = __builtin_amdgcn_readfirstlane(tid >> 6);
    int jb = colBase + wv * 16;
    const float* wbase = WT + (size_t)jb * 128;
    float acc[2][16];
    #pragma unroll
    for (int r = 0; r < 2; r++)
        #pragma unroll
        for (int i = 0; i < 16; i++) acc[r][i] = 0.f;

    for (int kt = 0; kt < 128; kt += 32) {
        __syncthreads();   // previous tile fully consumed
        #pragma unroll
        for (int q = 0; q < 4; q++) {
            int i = q * 256 + tid;          // [0,1024): 128 rows x 8 float4
            int r = i >> 3, f4 = i & 7;
            int gr = rowBase + r;
            float4 v = make_float4(0.f, 0.f, 0.f, 0.f);
            if (gr < N) v = ((const float4*)(X + (size_t)gr * 128 + kt))[f4];
            *(float4*)(xs + r * 33 + f4 * 4) = v;
        }
        __syncthreads();
        #pragma unroll
        for (int k0 = 0; k0 < 32; k0 += 4) {
            float4 xa = *(const float4*)(xs + lane * 33 + k0);
            float4 xb = *(const float4*)(xs + (lane + 64) * 33 + k0);
            #pragma unroll
            for (int i = 0; i < 16; i++) {
                const float* wr = wbase + i * 128 + kt + k0;  // uniform -> s_load
                float w0 = wr[0], w1 = wr[1], w2 = wr[2], w3 = wr[3];
                acc[0][i] = fmaf(xa.x, w0, acc[0][i]);
                acc[1][i] = fmaf(xb.x, w0, acc[1][i]);
                acc[0][i] = fmaf(xa.y, w1, acc[0][i]);
                acc[1][i] = fmaf(xb.y, w1, acc[1][i]);
                acc[0][i] = fmaf(xa.z, w2, acc[0][i]);
                acc[1][i] = fmaf(xb.z, w2, acc[1][i]);
                acc[0][i] = fmaf(xa.w, w3, acc[0][i]);
                acc[1][i] = fmaf(xb.w, w3, acc[1][i]);
            }
        }
    }
    int head = jb >> headShift;
    #pragma unroll
    for (int r = 0; r < 2; r++) {
        int row = rowBase + r * 64 + lane;
        if (row < N) {
            float pas = 0.f, pad_ = 0.f;
            #pragma unroll
            for (int i = 0; i < 16; i++) {
                pas  = fmaf(acc[r][i], atts[jb + i], pas);
                pad_ = fmaf(acc[r][i], attd[jb + i], pad_);
            }
            atomicAdd(oas + (size_t)row * H + head, pas);
            atomicAdd(oad + (size_t)row * H + head, pad_);
            uint4 w0, w1;
            w0.x = pkhalf2(acc[r][0],  acc[r][1]);
            w0.y = pkhalf2(acc[r][2],  acc[r][3]);
            w0.z = pkhalf2(acc[r][4],  acc[r][5]);
            w0.w = pkhalf2(acc[r][6],  acc[r][7]);
            w1.x = pkhalf2(acc[r][8],  acc[r][9]);
            w1.y = pkhalf2(acc[r][10], acc[r][11]);
            w1.z = pkhalf2(acc[r][12], acc[r][13]);
            w1.w = pkhalf2(acc[r][14], acc[r][15]);
            __half* op = OUT + (size_t)row * ncols + jb;
            *(uint4*)(op)     = w0;
            *(uint4*)(op + 8) = w1;
        }
    }
}

// ---- layer-1 edge pass: one wave per node; 16-edge chunks.
// Weights: lane=(el<<2)|hh. Gather: s via uniform s_load, 16 independent
// half2 gathers in flight in the cnt==16 fast path; lane owns channels
// {2lane, 2lane+1}.
__global__ void __launch_bounds__(256) edge1_kernel(
    const int* __restrict__ csr, const int* __restrict__ rowp,
    const __half2* __restrict__ h1, const float* __restrict__ as1,
    const float* __restrict__ ad1, const float* __restrict__ b1,
    float* __restrict__ x2, int N)
{
    int lane = threadIdx.x & 63;
    int n = __builtin_amdgcn_readfirstlane(blockIdx.x * 4 + (threadIdx.x >> 6));
    if (n >= N) return;
    int rs = rowp[n], re = rowp[n + 1];
    int hd = lane >> 4;
    int el = lane >> 2, hh = lane & 3;
    float adv = ad1[n * 4 + hh];
    float accx = 0.f, accy = 0.f, srun = 0.f;
    for (int base = rs; base < re; base += 16) {
        int cnt = re - base; if (cnt > 16) cnt = 16;
        float wv = 0.f;
        if (el < cnt) {
            int s = csr[base + el];
            float e = as1[s * 4 + hh] + adv;
            e = e > 0.f ? e : LRELU_SLOPE * e;
            wv = __expf(e);
        }
        float t = wv;
        t += __shfl_xor(t, 4);  t += __shfl_xor(t, 8);
        t += __shfl_xor(t, 16); t += __shfl_xor(t, 32);
        srun += t;
        if (cnt == 16) {
            #pragma unroll
            for (int e2 = 0; e2 < 16; ++e2) {
                int s = csr[base + e2];                    // uniform -> s_load
                float av = __shfl(wv, (e2 << 2) | hd);
                float2 v = __half22float2(h1[(size_t)s * 64 + lane]);
                accx = fmaf(av, v.x, accx);
                accy = fmaf(av, v.y, accy);
            }
        } else {
            for (int e2 = 0; e2 < cnt; ++e2) {
                int s = csr[base + e2];
                float av = __shfl(wv, (e2 << 2) | hd);
                float2 v = __half22float2(h1[(size_t)s * 64 + lane]);
                accx = fmaf(av, v.x, accx);
                accy = fmaf(av, v.y, accy);
            }
        }
    }
    float sden = __shfl(srun, hd) + 1e-16f;
    float inv = 1.f / sden;
    float2 bv = *(const float2*)(b1 + lane * 2);
    float o0 = accx * inv + bv.x;
    float o1 = accy * inv + bv.y;
    o0 = o0 > 0.f ? o0 : (__expf(o0) - 1.f);   // ELU
    o1 = o1 > 0.f ? o1 : (__expf(o1) - 1.f);
    *(float2*)(x2 + (size_t)n * 128 + lane * 2) = make_float2(o0, o1);
}

// ---- layer-2 edge pass (1 head, 64 channels; lane = channel) ----
__global__ void __launch_bounds__(256) edge2_kernel(
    const int* __restrict__ csr, const int* __restrict__ rowp,
    const __half* __restrict__ h2, const float* __restrict__ as2,
    const float* __restrict__ ad2, const float* __restrict__ b2,
    float* __restrict__ hf, int N)
{
    int lane = threadIdx.x & 63;
    int n = __builtin_amdgcn_readfirstlane(blockIdx.x * 4 + (threadIdx.x >> 6));
    if (n >= N) return;
    int rs = rowp[n], re = rowp[n + 1];
    float adv = ad2[n];
    float acc = 0.f, srun = 0.f;
    for (int base = rs; base < re; base += 16) {
        int cnt = re - base; if (cnt > 16) cnt = 16;
        float wv = 0.f;
        if (lane < cnt) {
            int s = csr[base + lane];
            float e = as2[s] + adv;
            e = e > 0.f ? e : LRELU_SLOPE * e;
            wv = __expf(e);
        }
        srun += wv;
        if (cnt == 16) {
            #pragma unroll
            for (int e2 = 0; e2 < 16; ++e2) {
                int s = csr[base + e2];                    // uniform -> s_load
                float av = __shfl(wv, e2);
                acc = fmaf(av, __half2float(h2[(size_t)s * 64 + lane]), acc);
            }
        } else {
            for (int e2 = 0; e2 < cnt; ++e2) {
                int s = csr[base + e2];
                float av = __shfl(wv, e2);
                acc = fmaf(av, __half2float(h2[(size_t)s * 64 + lane]), acc);
            }
        }
    }
    #pragma unroll
    for (int m = 1; m < 64; m <<= 1) srun += __shfl_xor(srun, m);
    float o = acc / (srun + 1e-16f) + b2[lane];
    hf[(size_t)n * 64 + lane] = o;
}

// ---- per-node MLP projections: u[n] = hf[n]@Wm1_top, v[n] = hf[n]@Wm1_bot --
// Output uv stored fp16 (gathered randomly by pair_mlp).
__global__ void __launch_bounds__(256) node_mlp_kernel(
    const float* __restrict__ hf, const float* __restrict__ Wm1T,
    __half* __restrict__ uv, int N)
{
    int lane = threadIdx.x & 63;
    int j = lane & 31, half = lane >> 5;
    const float* wr = Wm1T + j * 128 + half * 64;   // Wm1T[j][half*64 + k]
    float wreg[64];
    #pragma unroll
    for (int q = 0; q < 16; q++) {
        float4 t = ((const float4*)wr)[q];
        wreg[q*4] = t.x; wreg[q*4+1] = t.y; wreg[q*4+2] = t.z; wreg[q*4+3] = t.w;
    }
    int wgid = __builtin_amdgcn_readfirstlane(blockIdx.x * 4 + (threadIdx.x >> 6));
    int nwaves = gridDim.x * 4;
    for (int n = wgid; n < N; n += nwaves) {
        const float* hr = hf + (size_t)n * 64;
        float acc = 0.f;
        #pragma unroll
        for (int k = 0; k < 64; k += 4) {
            float4 hv = *(const float4*)(hr + k);   // uniform across wave
            acc = fmaf(hv.x, wreg[k],   acc);
            acc = fmaf(hv.y, wreg[k+1], acc);
            acc = fmaf(hv.z, wreg[k+2], acc);
            acc = fmaf(hv.w, wreg[k+3], acc);
        }
        uv[(size_t)n * 64 + lane] = __float2half_rn(acc);
    }
}

// ---- pair MLP: 2 lanes per pair (16 hidden units each), shfl-reduce ----
__global__ void __launch_bounds__(256) pair_mlp_kernel(
    const int* __restrict__ ps, const int* __restrict__ pd,
    const __half2* __restrict__ uv, const float* __restrict__ bm1,
    const float* __restrict__ Wm2, const float* __restrict__ bm2,
    float* __restrict__ out, int P)
{
    int gid = blockIdx.x * 256 + threadIdx.x;
    int p = gid >> 1;
    if (p >= P) return;
    int half = gid & 1;
    int j0 = half * 8;                                  // half2 offset (16 ch)
    int a = ps[p], b = pd[p];
    const __half2* ua = uv + (size_t)a * 32 + j0;       // u[a][16 ch]
    const __half2* vb = uv + (size_t)b * 32 + 16 + j0;  // v[b][16 ch]
    float r = 0.f;
    #pragma unroll
    for (int q = 0; q < 8; q++) {
        float2 uu = __half22float2(ua[q]);
        float2 vv = __half22float2(vb[q]);
        float2 bb = *(const float2*)(bm1 + half * 16 + q * 2);
        float2 ww = *(const float2*)(Wm2 + half * 16 + q * 2);
        float h0 = uu.x + vv.x + bb.x; h0 = h0 > 0.f ? h0 : 0.f; r = fmaf(h0, ww.x, r);
        float h1 = uu.y + vv.y + bb.y; h1 = h1 > 0.f ? h1 : 0.f; r = fmaf(h1, ww.y, r);
    }
    r += __shfl_xor(r, 1);
    if (half == 0) out[p] = r + bm2[0];
}

extern "C" void kernel_launch(void* const* d_in, const int* in_sizes, int n_in,
                              void* d_out, int out_size, void* d_ws, size_t ws_size,
                              hipStream_t stream)
{
    const float* x    = (const float*)d_in[0];
    const int*   ei   = (const int*)  d_in[1];
    const int*   ep   = (const int*)  d_in[2];
    const float* W1   = (const float*)d_in[3];
    const float* atS1 = (const float*)d_in[4];
    const float* atD1 = (const float*)d_in[5];
    const float* b1   = (const float*)d_in[6];
    const float* W2   = (const float*)d_in[7];
    const float* atS2 = (const float*)d_in[8];
    const float* atD2 = (const float*)d_in[9];
    const float* b2   = (const float*)d_in[10];
    const float* Wm1  = (const float*)d_in[11];
    const float* bm1  = (const float*)d_in[12];
    const float* Wm2  = (const float*)d_in[13];
    const float* bm2  = (const float*)d_in[14];
    float* out = (float*)d_out;

    int N = in_sizes[0] / 128;
    int E = in_sizes[1] / 2;
    int P = in_sizes[2] / 2;
    int Etot = E + N;

    // workspace carve (256B aligned)
    char* w = (char*)d_ws;
    auto alloc = [&](size_t bytes) {
        char* p = w; w += (bytes + 255) & ~(size_t)255; return p;
    };
    float*  W1T  = (float*)alloc(16384 * 4);
    float*  W2T  = (float*)alloc(8192 * 4);
    float*  Wm1T = (float*)alloc(4096 * 4);
    __half* h1   = (__half*)alloc((size_t)N * 128 * 2);  // fp16 gather table
    float*  x2   = (float*)alloc((size_t)N * 128 * 4);
    __half* h2   = (__half*)alloc((size_t)N * 64 * 2);   // fp16 gather table
    float*  hf   = (float*)alloc((size_t)N * 64 * 4);
    int*    rowp = (int*)alloc((size_t)(N + 1) * 4);
    int*    btot = (int*)alloc(64 * 4);
    int*    csrs = (int*)alloc((size_t)Etot * 4);
    // ---- contiguous zero-block (single memset) ----
    char* z0 = w;
    int*   deg  = (int*)alloc((size_t)N * 4);
    int*   curs = (int*)alloc((size_t)N * 4);
    float* as1  = (float*)alloc((size_t)N * 4 * 4);
    float* ad1  = (float*)alloc((size_t)N * 4 * 4);
    float* as2  = (float*)alloc((size_t)N * 4);
    float* ad2  = (float*)alloc((size_t)N * 4);
    char* z1 = w;
    __half* uv = (__half*)alloc((size_t)N * 64 * 2);     // fp16 gather table

    (void)hipMemsetAsync(z0, 0, (size_t)(z1 - z0), stream);

    prep_kernel<<<112, 256, 0, stream>>>(W1, W2, Wm1, W1T, W2T, Wm1T);

    int EN = E + N;
    hist_kernel<<<(EN + 255) / 256, 256, 0, stream>>>(ei + E, E, N, deg);
    int nb = (N + 1023) / 1024;
    scan1_kernel<<<nb, 1024, 0, stream>>>(deg, rowp, btot, N);
    scan2_kernel<<<1, 64, 0, stream>>>(btot, nb);
    scan3_kernel<<<nb, 1024, 0, stream>>>(rowp, btot, N);
    scatter_kernel<<<(EN + 255) / 256, 256, 0, stream>>>(ei, ei + E, E, N, rowp, curs, csrs);

    dim3 g1((N + 127) / 128, 2);
    gemm_att_kernel<<<g1, 256, 0, stream>>>(x, W1T, atS1, atD1, h1, as1, ad1,
                                            N, 128, 4, 5);
    edge1_kernel<<<(N + 3) / 4, 256, 0, stream>>>(csrs, rowp, (const __half2*)h1,
                                                  as1, ad1, b1, x2, N);
    dim3 g2((N + 127) / 128, 1);
    gemm_att_kernel<<<g2, 256, 0, stream>>>(x2, W2T, atS2, atD2, h2, as2, ad2,
                                            N, 64, 1, 6);
    edge2_kernel<<<(N + 3) / 4, 256, 0, stream>>>(csrs, rowp, h2, as2, ad2,
                                                  b2, hf, N);

    node_mlp_kernel<<<1024, 256, 0, stream>>>(hf, Wm1T, uv, N);
    pair_mlp_kernel<<<(2 * P + 255) / 256, 256, 0, stream>>>(ep, ep + P,
                                                             (const __half2*)uv,
                                                             bm1, Wm2, bm2, out, P);
}

// Round 7
// 286.921 us; speedup vs baseline: 1.0436x; 1.0436x over previous
//
#include <hip/hip_runtime.h>
#include <hip/hip_bf16.h>
#include <hip/hip_fp16.h>

// ---------------------------------------------------------------------------
// GAT link predictor: 2x GATConv + pair MLP.
// R7: register-tiled fp32 GEMM (64x64 tile, 4x4 micro-tile/thread, X and W^T
//     both in LDS, zero scalar loads in the K loop, plain-store att scores).
//     fp16 gather tables (h1, h2, uv), fp32 compute everywhere.
// ---------------------------------------------------------------------------

#define LRELU_SLOPE 0.2f

__device__ inline unsigned pkhalf2(float a, float b) {
    __half2 h = __floats2half2_rn(a, b);
    return *(unsigned*)&h;
}

// ---- weight pre-transpose (W1T/W2T: [col][k] for LDS staging) ----
__global__ void __launch_bounds__(256) prep_kernel(
    const float* __restrict__ W1, const float* __restrict__ W2,
    const float* __restrict__ Wm1,
    float* __restrict__ W1T, float* __restrict__ W2T, float* __restrict__ Wm1T)
{
    int i = blockIdx.x * 256 + threadIdx.x;
    if (i < 16384) {                       // W1 [128][128] -> W1T [128][128]
        int k = i >> 7, j = i & 127;
        W1T[j * 128 + k] = W1[i];
    } else if (i < 16384 + 8192) {         // W2 [128][64] -> W2T [64][128]
        int t = i - 16384;
        int k = t >> 6, j = t & 63;
        W2T[j * 128 + k] = W2[t];
    } else if (i < 16384 + 8192 + 4096) {  // Wm1 [128][32] -> Wm1T [32][128]
        int t = i - 24576;
        int k = t >> 5, j = t & 31;
        Wm1T[j * 128 + k] = Wm1[t];
    }
}

// ---- CSR build ----
__global__ void __launch_bounds__(256) hist_kernel(
    const int* __restrict__ dst, int E, int N, int* __restrict__ deg)
{
    int i = blockIdx.x * 256 + threadIdx.x;
    if (i >= E + N) return;
    int d = (i < E) ? dst[i] : (i - E);
    atomicAdd(deg + d, 1);
}

// hierarchical scan: per-1024-block inclusive scan + block totals
__global__ void __launch_bounds__(1024) scan1_kernel(
    const int* __restrict__ deg, int* __restrict__ rowp,
    int* __restrict__ btot, int n)
{
    __shared__ int wsum[16];
    int t = threadIdx.x, lane = t & 63, wid = t >> 6;
    int idx = blockIdx.x * 1024 + t;
    int v = (idx < n) ? deg[idx] : 0;
    #pragma unroll
    for (int off = 1; off < 64; off <<= 1) {
        int y = __shfl_up(v, off);
        if (lane >= off) v += y;
    }
    if (lane == 63) wsum[wid] = v;
    __syncthreads();
    if (wid == 0) {
        int s = (lane < 16) ? wsum[lane] : 0;
        #pragma unroll
        for (int off = 1; off < 16; off <<= 1) {
            int y = __shfl_up(s, off);
            if (lane >= off) s += y;
        }
        if (lane < 16) wsum[lane] = s;
    }
    __syncthreads();
    if (wid > 0) v += wsum[wid - 1];
    if (idx < n) rowp[idx + 1] = v;
    if (t == 1023) btot[blockIdx.x] = v;
    if (idx == 0) rowp[0] = 0;
}

__global__ void __launch_bounds__(64) scan2_kernel(int* __restrict__ btot, int nb)
{
    int lane = threadIdx.x;
    int v = (lane < nb) ? btot[lane] : 0;
    #pragma unroll
    for (int off = 1; off < 64; off <<= 1) {
        int y = __shfl_up(v, off);
        if (lane >= off) v += y;
    }
    if (lane < nb) btot[lane] = v;
}

__global__ void __launch_bounds__(1024) scan3_kernel(
    int* __restrict__ rowp, const int* __restrict__ btot, int n)
{
    if (blockIdx.x == 0) return;
    int idx = blockIdx.x * 1024 + threadIdx.x;
    if (idx < n) rowp[idx + 1] += btot[blockIdx.x - 1];
}

__global__ void __launch_bounds__(256) scatter_kernel(
    const int* __restrict__ src, const int* __restrict__ dst, int E, int N,
    const int* __restrict__ rowptr, int* __restrict__ cursor,
    int* __restrict__ csrs)
{
    int i = blockIdx.x * 256 + threadIdx.x;
    if (i >= E + N) return;
    int s, d;
    if (i < E) { s = src[i]; d = dst[i]; } else { s = d = i - E; }
    int pos = rowptr[d] + atomicAdd(cursor + d, 1);
    csrs[pos] = s;
}

// ---- fused GEMM + attention-score epilogue; OUT stored fp16 ----
// Block 256 thr, tile 64 rows x 64 cols, thread = 4x4 micro-tile
// (tx=tid&15 -> cols, ty=tid>>4 -> rows). X tile and W^T tile in LDS,
// stride 33 (2-way max -> free). K loop: 8 ds_read_b128 + 64 v_fma per
// 4-k chunk, no scalar loads. Scores: single-writer plain stores.
__global__ void __launch_bounds__(256) gemm_att_kernel(
    const float* __restrict__ X, const float* __restrict__ WT,
    const float* __restrict__ atts, const float* __restrict__ attd,
    __half* __restrict__ OUT, float* __restrict__ oas, float* __restrict__ oad,
    int N, int ncols, int H, int headShift)
{
    __shared__ float xls[64 * 33];
    __shared__ float wls[64 * 33];
    int tid = threadIdx.x;
    int rowBase = blockIdx.x * 64;
    int colBase = blockIdx.y * 64;
    int tx = tid & 15, ty = tid >> 4;
    float acc[4][4];
    #pragma unroll
    for (int r = 0; r < 4; r++)
        #pragma unroll
        for (int c = 0; c < 4; c++) acc[r][c] = 0.f;

    for (int kt = 0; kt < 128; kt += 32) {
        __syncthreads();   // previous tile fully consumed
        #pragma unroll
        for (int q = 0; q < 2; q++) {
            int i = q * 256 + tid;          // [0,512): 64 rows x 8 float4
            int r = i >> 3, f4 = i & 7;
            int gr = rowBase + r;
            float4 xv = make_float4(0.f, 0.f, 0.f, 0.f);
            if (gr < N) xv = ((const float4*)(X + (size_t)gr * 128 + kt))[f4];
            *(float4*)(xls + r * 33 + f4 * 4) = xv;
            float4 wv = ((const float4*)(WT + (size_t)(colBase + r) * 128 + kt))[f4];
            *(float4*)(wls + r * 33 + f4 * 4) = wv;
        }
        __syncthreads();
        #pragma unroll
        for (int kc = 0; kc < 8; kc++) {
            float4 xr[4], wr[4];
            #pragma unroll
            for (int r = 0; r < 4; r++)
                xr[r] = *(const float4*)(xls + (ty * 4 + r) * 33 + kc * 4);
            #pragma unroll
            for (int c = 0; c < 4; c++)
                wr[c] = *(const float4*)(wls + (tx * 4 + c) * 33 + kc * 4);
            #pragma unroll
            for (int r = 0; r < 4; r++)
                #pragma unroll
                for (int c = 0; c < 4; c++) {
                    acc[r][c] = fmaf(xr[r].x, wr[c].x, acc[r][c]);
                    acc[r][c] = fmaf(xr[r].y, wr[c].y, acc[r][c]);
                    acc[r][c] = fmaf(xr[r].z, wr[c].z, acc[r][c]);
                    acc[r][c] = fmaf(xr[r].w, wr[c].w, acc[r][c]);
                }
        }
    }

    int col0 = colBase + tx * 4;
    float4 av = *(const float4*)(atts + col0);
    float4 dv = *(const float4*)(attd + col0);
    int txPerHead = (1 << headShift) >> 2;   // 8 (32-col heads) or 16
    int head = col0 >> headShift;
    #pragma unroll
    for (int r = 0; r < 4; r++) {
        int row = rowBase + ty * 4 + r;
        float pas = acc[r][0] * av.x + acc[r][1] * av.y
                  + acc[r][2] * av.z + acc[r][3] * av.w;
        float pad_ = acc[r][0] * dv.x + acc[r][1] * dv.y
                   + acc[r][2] * dv.z + acc[r][3] * dv.w;
        for (int m = 1; m < txPerHead; m <<= 1) {
            pas  += __shfl_xor(pas, m);
            pad_ += __shfl_xor(pad_, m);
        }
        if (row < N) {
            if ((tx & (txPerHead - 1)) == 0) {
                oas[(size_t)row * H + head] = pas;
                oad[(size_t)row * H + head] = pad_;
            }
            uint2 hw;
            hw.x = pkhalf2(acc[r][0], acc[r][1]);
            hw.y = pkhalf2(acc[r][2], acc[r][3]);
            *(uint2*)(OUT + (size_t)row * ncols + col0) = hw;
        }
    }
}

// ---- layer-1 edge pass: one wave per node; 16-edge chunks.
// Weights: lane=(el<<2)|hh. Gather: s via uniform s_load, 16 independent
// half2 gathers in flight in the cnt==16 fast path; lane owns channels
// {2lane, 2lane+1}.
__global__ void __launch_bounds__(256) edge1_kernel(
    const int* __restrict__ csr, const int* __restrict__ rowp,
    const __half2* __restrict__ h1, const float* __restrict__ as1,
    const float* __restrict__ ad1, const float* __restrict__ b1,
    float* __restrict__ x2, int N)
{
    int lane = threadIdx.x & 63;
    int n = __builtin_amdgcn_readfirstlane(blockIdx.x * 4 + (threadIdx.x >> 6));
    if (n >= N) return;
    int rs = rowp[n], re = rowp[n + 1];
    int hd = lane >> 4;
    int el = lane >> 2, hh = lane & 3;
    float adv = ad1[n * 4 + hh];
    float accx = 0.f, accy = 0.f, srun = 0.f;
    for (int base = rs; base < re; base += 16) {
        int cnt = re - base; if (cnt > 16) cnt = 16;
        float wv = 0.f;
        if (el < cnt) {
            int s = csr[base + el];
            float e = as1[s * 4 + hh] + adv;
            e = e > 0.f ? e : LRELU_SLOPE * e;
            wv = __expf(e);
        }
        float t = wv;
        t += __shfl_xor(t, 4);  t += __shfl_xor(t, 8);
        t += __shfl_xor(t, 16); t += __shfl_xor(t, 32);
        srun += t;
        if (cnt == 16) {
            #pragma unroll
            for (int e2 = 0; e2 < 16; ++e2) {
                int s = csr[base + e2];                    // uniform -> s_load
                float av = __shfl(wv, (e2 << 2) | hd);
                float2 v = __half22float2(h1[(size_t)s * 64 + lane]);
                accx = fmaf(av, v.x, accx);
                accy = fmaf(av, v.y, accy);
            }
        } else {
            for (int e2 = 0; e2 < cnt; ++e2) {
                int s = csr[base + e2];
                float av = __shfl(wv, (e2 << 2) | hd);
                float2 v = __half22float2(h1[(size_t)s * 64 + lane]);
                accx = fmaf(av, v.x, accx);
                accy = fmaf(av, v.y, accy);
            }
        }
    }
    float sden = __shfl(srun, hd) + 1e-16f;
    float inv = 1.f / sden;
    float2 bv = *(const float2*)(b1 + lane * 2);
    float o0 = accx * inv + bv.x;
    float o1 = accy * inv + bv.y;
    o0 = o0 > 0.f ? o0 : (__expf(o0) - 1.f);   // ELU
    o1 = o1 > 0.f ? o1 : (__expf(o1) - 1.f);
    *(float2*)(x2 + (size_t)n * 128 + lane * 2) = make_float2(o0, o1);
}

// ---- layer-2 edge pass (1 head, 64 channels; lane = channel) ----
__global__ void __launch_bounds__(256) edge2_kernel(
    const int* __restrict__ csr, const int* __restrict__ rowp,
    const __half* __restrict__ h2, const float* __restrict__ as2,
    const float* __restrict__ ad2, const float* __restrict__ b2,
    float* __restrict__ hf, int N)
{
    int lane = threadIdx.x & 63;
    int n = __builtin_amdgcn_readfirstlane(blockIdx.x * 4 + (threadIdx.x >> 6));
    if (n >= N) return;
    int rs = rowp[n], re = rowp[n + 1];
    float adv = ad2[n];
    float acc = 0.f, srun = 0.f;
    for (int base = rs; base < re; base += 16) {
        int cnt = re - base; if (cnt > 16) cnt = 16;
        float wv = 0.f;
        if (lane < cnt) {
            int s = csr[base + lane];
            float e = as2[s] + adv;
            e = e > 0.f ? e : LRELU_SLOPE * e;
            wv = __expf(e);
        }
        srun += wv;
        if (cnt == 16) {
            #pragma unroll
            for (int e2 = 0; e2 < 16; ++e2) {
                int s = csr[base + e2];                    // uniform -> s_load
                float av = __shfl(wv, e2);
                acc = fmaf(av, __half2float(h2[(size_t)s * 64 + lane]), acc);
            }
        } else {
            for (int e2 = 0; e2 < cnt; ++e2) {
                int s = csr[base + e2];
                float av = __shfl(wv, e2);
                acc = fmaf(av, __half2float(h2[(size_t)s * 64 + lane]), acc);
            }
        }
    }
    #pragma unroll
    for (int m = 1; m < 64; m <<= 1) srun += __shfl_xor(srun, m);
    float o = acc / (srun + 1e-16f) + b2[lane];
    hf[(size_t)n * 64 + lane] = o;
}

// ---- per-node MLP projections: u[n] = hf[n]@Wm1_top, v[n] = hf[n]@Wm1_bot --
// Output uv stored fp16 (gathered randomly by pair_mlp).
__global__ void __launch_bounds__(256) node_mlp_kernel(
    const float* __restrict__ hf, const float* __restrict__ Wm1T,
    __half* __restrict__ uv, int N)
{
    int lane = threadIdx.x & 63;
    int j = lane & 31, half = lane >> 5;
    const float* wr = Wm1T + j * 128 + half * 64;   // Wm1T[j][half*64 + k]
    float wreg[64];
    #pragma unroll
    for (int q = 0; q < 16; q++) {
        float4 t = ((const float4*)wr)[q];
        wreg[q*4] = t.x; wreg[q*4+1] = t.y; wreg[q*4+2] = t.z; wreg[q*4+3] = t.w;
    }
    int wgid = __builtin_amdgcn_readfirstlane(blockIdx.x * 4 + (threadIdx.x >> 6));
    int nwaves = gridDim.x * 4;
    for (int n = wgid; n < N; n += nwaves) {
        const float* hr = hf + (size_t)n * 64;
        float acc = 0.f;
        #pragma unroll
        for (int k = 0; k < 64; k += 4) {
            float4 hv = *(const float4*)(hr + k);   // uniform across wave
            acc = fmaf(hv.x, wreg[k],   acc);
            acc = fmaf(hv.y, wreg[k+1], acc);
            acc = fmaf(hv.z, wreg[k+2], acc);
            acc = fmaf(hv.w, wreg[k+3], acc);
        }
        uv[(size_t)n * 64 + lane] = __float2half_rn(acc);
    }
}

// ---- pair MLP: 2 lanes per pair (16 hidden units each), shfl-reduce ----
__global__ void __launch_bounds__(256) pair_mlp_kernel(
    const int* __restrict__ ps, const int* __restrict__ pd,
    const __half2* __restrict__ uv, const float* __restrict__ bm1,
    const float* __restrict__ Wm2, const float* __restrict__ bm2,
    float* __restrict__ out, int P)
{
    int gid = blockIdx.x * 256 + threadIdx.x;
    int p = gid >> 1;
    if (p >= P) return;
    int half = gid & 1;
    int j0 = half * 8;                                  // half2 offset (16 ch)
    int a = ps[p], b = pd[p];
    const __half2* ua = uv + (size_t)a * 32 + j0;       // u[a][16 ch]
    const __half2* vb = uv + (size_t)b * 32 + 16 + j0;  // v[b][16 ch]
    float r = 0.f;
    #pragma unroll
    for (int q = 0; q < 8; q++) {
        float2 uu = __half22float2(ua[q]);
        float2 vv = __half22float2(vb[q]);
        float2 bb = *(const float2*)(bm1 + half * 16 + q * 2);
        float2 ww = *(const float2*)(Wm2 + half * 16 + q * 2);
        float h0 = uu.x + vv.x + bb.x; h0 = h0 > 0.f ? h0 : 0.f; r = fmaf(h0, ww.x, r);
        float h1 = uu.y + vv.y + bb.y; h1 = h1 > 0.f ? h1 : 0.f; r = fmaf(h1, ww.y, r);
    }
    r += __shfl_xor(r, 1);
    if (half == 0) out[p] = r + bm2[0];
}

extern "C" void kernel_launch(void* const* d_in, const int* in_sizes, int n_in,
                              void* d_out, int out_size, void* d_ws, size_t ws_size,
                              hipStream_t stream)
{
    const float* x    = (const float*)d_in[0];
    const int*   ei   = (const int*)  d_in[1];
    const int*   ep   = (const int*)  d_in[2];
    const float* W1   = (const float*)d_in[3];
    const float* atS1 = (const float*)d_in[4];
    const float* atD1 = (const float*)d_in[5];
    const float* b1   = (const float*)d_in[6];
    const float* W2   = (const float*)d_in[7];
    const float* atS2 = (const float*)d_in[8];
    const float* atD2 = (const float*)d_in[9];
    const float* b2   = (const float*)d_in[10];
    const float* Wm1  = (const float*)d_in[11];
    const float* bm1  = (const float*)d_in[12];
    const float* Wm2  = (const float*)d_in[13];
    const float* bm2  = (const float*)d_in[14];
    float* out = (float*)d_out;

    int N = in_sizes[0] / 128;
    int E = in_sizes[1] / 2;
    int P = in_sizes[2] / 2;
    int Etot = E + N;

    // workspace carve (256B aligned)
    char* w = (char*)d_ws;
    auto alloc = [&](size_t bytes) {
        char* p = w; w += (bytes + 255) & ~(size_t)255; return p;
    };
    float*  W1T  = (float*)alloc(16384 * 4);
    float*  W2T  = (float*)alloc(8192 * 4);
    float*  Wm1T = (float*)alloc(4096 * 4);
    __half* h1   = (__half*)alloc((size_t)N * 128 * 2);  // fp16 gather table
    float*  x2   = (float*)alloc((size_t)N * 128 * 4);
    __half* h2   = (__half*)alloc((size_t)N * 64 * 2);   // fp16 gather table
    float*  hf   = (float*)alloc((size_t)N * 64 * 4);
    int*    rowp = (int*)alloc((size_t)(N + 1) * 4);
    int*    btot = (int*)alloc(64 * 4);
    int*    csrs = (int*)alloc((size_t)Etot * 4);
    // ---- contiguous zero-block (single memset) ----
    char* z0 = w;
    int*   deg  = (int*)alloc((size_t)N * 4);
    int*   curs = (int*)alloc((size_t)N * 4);
    char* z1 = w;
    float* as1  = (float*)alloc((size_t)N * 4 * 4);
    float* ad1  = (float*)alloc((size_t)N * 4 * 4);
    float* as2  = (float*)alloc((size_t)N * 4);
    float* ad2  = (float*)alloc((size_t)N * 4);
    __half* uv = (__half*)alloc((size_t)N * 64 * 2);     // fp16 gather table

    (void)hipMemsetAsync(z0, 0, (size_t)(z1 - z0), stream);

    prep_kernel<<<112, 256, 0, stream>>>(W1, W2, Wm1, W1T, W2T, Wm1T);

    int EN = E + N;
    hist_kernel<<<(EN + 255) / 256, 256, 0, stream>>>(ei + E, E, N, deg);
    int nb = (N + 1023) / 1024;
    scan1_kernel<<<nb, 1024, 0, stream>>>(deg, rowp, btot, N);
    scan2_kernel<<<1, 64, 0, stream>>>(btot, nb);
    scan3_kernel<<<nb, 1024, 0, stream>>>(rowp, btot, N);
    scatter_kernel<<<(EN + 255) / 256, 256, 0, stream>>>(ei, ei + E, E, N, rowp, curs, csrs);

    dim3 g1((N + 63) / 64, 2);
    gemm_att_kernel<<<g1, 256, 0, stream>>>(x, W1T, atS1, atD1, h1, as1, ad1,
                                            N, 128, 4, 5);
    edge1_kernel<<<(N + 3) / 4, 256, 0, stream>>>(csrs, rowp, (const __half2*)h1,
                                                  as1, ad1, b1, x2, N);
    dim3 g2((N + 63) / 64, 1);
    gemm_att_kernel<<<g2, 256, 0, stream>>>(x2, W2T, atS2, atD2, h2, as2, ad2,
                                            N, 64, 1, 6);
    edge2_kernel<<<(N + 3) / 4, 256, 0, stream>>>(csrs, rowp, h2, as2, ad2,
                                                  b2, hf, N);

    node_mlp_kernel<<<1024, 256, 0, stream>>>(hf, Wm1T, uv, N);
    pair_mlp_kernel<<<(2 * P + 255) / 256, 256, 0, stream>>>(ep, ep + P,
                                                             (const __half2*)uv,
                                                             bm1, Wm2, bm2, out, P);
}

// Round 8
// 279.236 us; speedup vs baseline: 1.0723x; 1.0275x over previous
//
#include <hip/hip_runtime.h>
#include <hip/hip_bf16.h>
#include <hip/hip_fp16.h>

// ---------------------------------------------------------------------------
// GAT link predictor: 2x GATConv + pair MLP.
// R8: edge kernels restructured as fully-unrolled 32-slot padded chunks:
//     all 32 row-gathers staged to registers back-to-back (2x MLP vs R7,
//     no serial remainder path). Register-tiled fp32 GEMM, fp16 gather
//     tables, factorized MLP.
// ---------------------------------------------------------------------------

#define LRELU_SLOPE 0.2f

__device__ inline unsigned pkhalf2(float a, float b) {
    __half2 h = __floats2half2_rn(a, b);
    return *(unsigned*)&h;
}

// ---- weight pre-transpose (W1T/W2T: [col][k] for LDS staging) ----
__global__ void __launch_bounds__(256) prep_kernel(
    const float* __restrict__ W1, const float* __restrict__ W2,
    const float* __restrict__ Wm1,
    float* __restrict__ W1T, float* __restrict__ W2T, float* __restrict__ Wm1T)
{
    int i = blockIdx.x * 256 + threadIdx.x;
    if (i < 16384) {                       // W1 [128][128] -> W1T [128][128]
        int k = i >> 7, j = i & 127;
        W1T[j * 128 + k] = W1[i];
    } else if (i < 16384 + 8192) {         // W2 [128][64] -> W2T [64][128]
        int t = i - 16384;
        int k = t >> 6, j = t & 63;
        W2T[j * 128 + k] = W2[t];
    } else if (i < 16384 + 8192 + 4096) {  // Wm1 [128][32] -> Wm1T [32][128]
        int t = i - 24576;
        int k = t >> 5, j = t & 31;
        Wm1T[j * 128 + k] = Wm1[t];
    }
}

// ---- CSR build ----
__global__ void __launch_bounds__(256) hist_kernel(
    const int* __restrict__ dst, int E, int N, int* __restrict__ deg)
{
    int i = blockIdx.x * 256 + threadIdx.x;
    if (i >= E + N) return;
    int d = (i < E) ? dst[i] : (i - E);
    atomicAdd(deg + d, 1);
}

// hierarchical scan: per-1024-block inclusive scan + block totals
__global__ void __launch_bounds__(1024) scan1_kernel(
    const int* __restrict__ deg, int* __restrict__ rowp,
    int* __restrict__ btot, int n)
{
    __shared__ int wsum[16];
    int t = threadIdx.x, lane = t & 63, wid = t >> 6;
    int idx = blockIdx.x * 1024 + t;
    int v = (idx < n) ? deg[idx] : 0;
    #pragma unroll
    for (int off = 1; off < 64; off <<= 1) {
        int y = __shfl_up(v, off);
        if (lane >= off) v += y;
    }
    if (lane == 63) wsum[wid] = v;
    __syncthreads();
    if (wid == 0) {
        int s = (lane < 16) ? wsum[lane] : 0;
        #pragma unroll
        for (int off = 1; off < 16; off <<= 1) {
            int y = __shfl_up(s, off);
            if (lane >= off) s += y;
        }
        if (lane < 16) wsum[lane] = s;
    }
    __syncthreads();
    if (wid > 0) v += wsum[wid - 1];
    if (idx < n) rowp[idx + 1] = v;
    if (t == 1023) btot[blockIdx.x] = v;
    if (idx == 0) rowp[0] = 0;
}

__global__ void __launch_bounds__(64) scan2_kernel(int* __restrict__ btot, int nb)
{
    int lane = threadIdx.x;
    int v = (lane < nb) ? btot[lane] : 0;
    #pragma unroll
    for (int off = 1; off < 64; off <<= 1) {
        int y = __shfl_up(v, off);
        if (lane >= off) v += y;
    }
    if (lane < nb) btot[lane] = v;
}

__global__ void __launch_bounds__(1024) scan3_kernel(
    int* __restrict__ rowp, const int* __restrict__ btot, int n)
{
    if (blockIdx.x == 0) return;
    int idx = blockIdx.x * 1024 + threadIdx.x;
    if (idx < n) rowp[idx + 1] += btot[blockIdx.x - 1];
}

__global__ void __launch_bounds__(256) scatter_kernel(
    const int* __restrict__ src, const int* __restrict__ dst, int E, int N,
    const int* __restrict__ rowptr, int* __restrict__ cursor,
    int* __restrict__ csrs)
{
    int i = blockIdx.x * 256 + threadIdx.x;
    if (i >= E + N) return;
    int s, d;
    if (i < E) { s = src[i]; d = dst[i]; } else { s = d = i - E; }
    int pos = rowptr[d] + atomicAdd(cursor + d, 1);
    csrs[pos] = s;
}

// ---- fused GEMM + attention-score epilogue; OUT stored fp16 ----
// Block 256 thr, tile 64 rows x 64 cols, thread = 4x4 micro-tile
// (tx=tid&15 -> cols, ty=tid>>4 -> rows). X tile and W^T tile in LDS,
// stride 33 (2-way max -> free). K loop: 8 ds_read_b128 + 64 v_fma per
// 4-k chunk, no scalar loads. Scores: single-writer plain stores.
__global__ void __launch_bounds__(256) gemm_att_kernel(
    const float* __restrict__ X, const float* __restrict__ WT,
    const float* __restrict__ atts, const float* __restrict__ attd,
    __half* __restrict__ OUT, float* __restrict__ oas, float* __restrict__ oad,
    int N, int ncols, int H, int headShift)
{
    __shared__ float xls[64 * 33];
    __shared__ float wls[64 * 33];
    int tid = threadIdx.x;
    int rowBase = blockIdx.x * 64;
    int colBase = blockIdx.y * 64;
    int tx = tid & 15, ty = tid >> 4;
    float acc[4][4];
    #pragma unroll
    for (int r = 0; r < 4; r++)
        #pragma unroll
        for (int c = 0; c < 4; c++) acc[r][c] = 0.f;

    for (int kt = 0; kt < 128; kt += 32) {
        __syncthreads();   // previous tile fully consumed
        #pragma unroll
        for (int q = 0; q < 2; q++) {
            int i = q * 256 + tid;          // [0,512): 64 rows x 8 float4
            int r = i >> 3, f4 = i & 7;
            int gr = rowBase + r;
            float4 xv = make_float4(0.f, 0.f, 0.f, 0.f);
            if (gr < N) xv = ((const float4*)(X + (size_t)gr * 128 + kt))[f4];
            *(float4*)(xls + r * 33 + f4 * 4) = xv;
            float4 wv = ((const float4*)(WT + (size_t)(colBase + r) * 128 + kt))[f4];
            *(float4*)(wls + r * 33 + f4 * 4) = wv;
        }
        __syncthreads();
        #pragma unroll
        for (int kc = 0; kc < 8; kc++) {
            float4 xr[4], wr[4];
            #pragma unroll
            for (int r = 0; r < 4; r++)
                xr[r] = *(const float4*)(xls + (ty * 4 + r) * 33 + kc * 4);
            #pragma unroll
            for (int c = 0; c < 4; c++)
                wr[c] = *(const float4*)(wls + (tx * 4 + c) * 33 + kc * 4);
            #pragma unroll
            for (int r = 0; r < 4; r++)
                #pragma unroll
                for (int c = 0; c < 4; c++) {
                    acc[r][c] = fmaf(xr[r].x, wr[c].x, acc[r][c]);
                    acc[r][c] = fmaf(xr[r].y, wr[c].y, acc[r][c]);
                    acc[r][c] = fmaf(xr[r].z, wr[c].z, acc[r][c]);
                    acc[r][c] = fmaf(xr[r].w, wr[c].w, acc[r][c]);
                }
        }
    }

    int col0 = colBase + tx * 4;
    float4 av = *(const float4*)(atts + col0);
    float4 dv = *(const float4*)(attd + col0);
    int txPerHead = (1 << headShift) >> 2;   // 8 (32-col heads) or 16
    int head = col0 >> headShift;
    #pragma unroll
    for (int r = 0; r < 4; r++) {
        int row = rowBase + ty * 4 + r;
        float pas = acc[r][0] * av.x + acc[r][1] * av.y
                  + acc[r][2] * av.z + acc[r][3] * av.w;
        float pad_ = acc[r][0] * dv.x + acc[r][1] * dv.y
                   + acc[r][2] * dv.z + acc[r][3] * dv.w;
        for (int m = 1; m < txPerHead; m <<= 1) {
            pas  += __shfl_xor(pas, m);
            pad_ += __shfl_xor(pad_, m);
        }
        if (row < N) {
            if ((tx & (txPerHead - 1)) == 0) {
                oas[(size_t)row * H + head] = pas;
                oad[(size_t)row * H + head] = pad_;
            }
            uint2 hw;
            hw.x = pkhalf2(acc[r][0], acc[r][1]);
            hw.y = pkhalf2(acc[r][2], acc[r][3]);
            *(uint2*)(OUT + (size_t)row * ncols + col0) = hw;
        }
    }
}

// ---- layer-1 edge pass: one wave per node; fully-unrolled 32-slot chunks.
// Alpha: two 16-slot halves, lane=(el<<2)|hh, zero-padded past cnt.
// Gather: 32 independent half2 loads staged to registers (padded slots
// clamp to the last valid edge -> same-line hit). lane owns channels
// {2lane, 2lane+1}.
__global__ void __launch_bounds__(256) edge1_kernel(
    const int* __restrict__ csr, const int* __restrict__ rowp,
    const __half2* __restrict__ h1, const float* __restrict__ as1,
    const float* __restrict__ ad1, const float* __restrict__ b1,
    float* __restrict__ x2, int N)
{
    int lane = threadIdx.x & 63;
    int n = __builtin_amdgcn_readfirstlane(blockIdx.x * 4 + (threadIdx.x >> 6));
    if (n >= N) return;
    int rs = rowp[n], re = rowp[n + 1];
    int hd = lane >> 4;
    int el = lane >> 2, hh = lane & 3;
    float adv = ad1[n * 4 + hh];
    float accx = 0.f, accy = 0.f, srun = 0.f;
    for (int base = rs; base < re; base += 32) {
        int cnt = re - base; if (cnt > 32) cnt = 32;
        float wvA = 0.f, wvB = 0.f;
        if (el < cnt) {
            int s = csr[base + el];
            float e = as1[s * 4 + hh] + adv;
            e = e > 0.f ? e : LRELU_SLOPE * e;
            wvA = __expf(e);
        }
        if (el + 16 < cnt) {
            int s = csr[base + 16 + el];
            float e = as1[s * 4 + hh] + adv;
            e = e > 0.f ? e : LRELU_SLOPE * e;
            wvB = __expf(e);
        }
        float t = wvA + wvB;
        t += __shfl_xor(t, 4);  t += __shfl_xor(t, 8);
        t += __shfl_xor(t, 16); t += __shfl_xor(t, 32);
        srun += t;
        // stage 32 gathers back-to-back (all independent, deep vmcnt queue)
        __half2 hv[32];
        #pragma unroll
        for (int e2 = 0; e2 < 32; ++e2) {
            int ee = e2 < cnt ? e2 : cnt - 1;      // wave-uniform clamp
            int s = csr[base + ee];                // uniform -> s_load
            hv[e2] = h1[(size_t)s * 64 + lane];
        }
        #pragma unroll
        for (int e2 = 0; e2 < 32; ++e2) {
            float av = (e2 < 16) ? __shfl(wvA, (e2 << 2) | hd)
                                 : __shfl(wvB, ((e2 - 16) << 2) | hd);
            float2 v = __half22float2(hv[e2]);
            accx = fmaf(av, v.x, accx);
            accy = fmaf(av, v.y, accy);
        }
    }
    float sden = __shfl(srun, hd) + 1e-16f;
    float inv = 1.f / sden;
    float2 bv = *(const float2*)(b1 + lane * 2);
    float o0 = accx * inv + bv.x;
    float o1 = accy * inv + bv.y;
    o0 = o0 > 0.f ? o0 : (__expf(o0) - 1.f);   // ELU
    o1 = o1 > 0.f ? o1 : (__expf(o1) - 1.f);
    *(float2*)(x2 + (size_t)n * 128 + lane * 2) = make_float2(o0, o1);
}

// ---- layer-2 edge pass (1 head, 64 channels; lane = channel), 32-slot ----
__global__ void __launch_bounds__(256) edge2_kernel(
    const int* __restrict__ csr, const int* __restrict__ rowp,
    const __half* __restrict__ h2, const float* __restrict__ as2,
    const float* __restrict__ ad2, const float* __restrict__ b2,
    float* __restrict__ hf, int N)
{
    int lane = threadIdx.x & 63;
    int n = __builtin_amdgcn_readfirstlane(blockIdx.x * 4 + (threadIdx.x >> 6));
    if (n >= N) return;
    int rs = rowp[n], re = rowp[n + 1];
    float adv = ad2[n];
    float acc = 0.f, srun = 0.f;
    for (int base = rs; base < re; base += 32) {
        int cnt = re - base; if (cnt > 32) cnt = 32;
        float wv = 0.f;
        if (lane < cnt) {
            int s = csr[base + lane];
            float e = as2[s] + adv;
            e = e > 0.f ? e : LRELU_SLOPE * e;
            wv = __expf(e);
        }
        srun += wv;
        __half hv[32];
        #pragma unroll
        for (int e2 = 0; e2 < 32; ++e2) {
            int ee = e2 < cnt ? e2 : cnt - 1;      // wave-uniform clamp
            int s = csr[base + ee];                // uniform -> s_load
            hv[e2] = h2[(size_t)s * 64 + lane];
        }
        #pragma unroll
        for (int e2 = 0; e2 < 32; ++e2) {
            float av = __shfl(wv, e2);             // 0 for padded slots
            acc = fmaf(av, __half2float(hv[e2]), acc);
        }
    }
    #pragma unroll
    for (int m = 1; m < 64; m <<= 1) srun += __shfl_xor(srun, m);
    float o = acc / (srun + 1e-16f) + b2[lane];
    hf[(size_t)n * 64 + lane] = o;
}

// ---- per-node MLP projections: u[n] = hf[n]@Wm1_top, v[n] = hf[n]@Wm1_bot --
// Output uv stored fp16 (gathered randomly by pair_mlp).
__global__ void __launch_bounds__(256) node_mlp_kernel(
    const float* __restrict__ hf, const float* __restrict__ Wm1T,
    __half* __restrict__ uv, int N)
{
    int lane = threadIdx.x & 63;
    int j = lane & 31, half = lane >> 5;
    const float* wr = Wm1T + j * 128 + half * 64;   // Wm1T[j][half*64 + k]
    float wreg[64];
    #pragma unroll
    for (int q = 0; q < 16; q++) {
        float4 t = ((const float4*)wr)[q];
        wreg[q*4] = t.x; wreg[q*4+1] = t.y; wreg[q*4+2] = t.z; wreg[q*4+3] = t.w;
    }
    int wgid = __builtin_amdgcn_readfirstlane(blockIdx.x * 4 + (threadIdx.x >> 6));
    int nwaves = gridDim.x * 4;
    for (int n = wgid; n < N; n += nwaves) {
        const float* hr = hf + (size_t)n * 64;
        float acc = 0.f;
        #pragma unroll
        for (int k = 0; k < 64; k += 4) {
            float4 hv = *(const float4*)(hr + k);   // uniform across wave
            acc = fmaf(hv.x, wreg[k],   acc);
            acc = fmaf(hv.y, wreg[k+1], acc);
            acc = fmaf(hv.z, wreg[k+2], acc);
            acc = fmaf(hv.w, wreg[k+3], acc);
        }
        uv[(size_t)n * 64 + lane] = __float2half_rn(acc);
    }
}

// ---- pair MLP: 2 lanes per pair (16 hidden units each), shfl-reduce ----
__global__ void __launch_bounds__(256) pair_mlp_kernel(
    const int* __restrict__ ps, const int* __restrict__ pd,
    const __half2* __restrict__ uv, const float* __restrict__ bm1,
    const float* __restrict__ Wm2, const float* __restrict__ bm2,
    float* __restrict__ out, int P)
{
    int gid = blockIdx.x * 256 + threadIdx.x;
    int p = gid >> 1;
    if (p >= P) return;
    int half = gid & 1;
    int j0 = half * 8;                                  // half2 offset (16 ch)
    int a = ps[p], b = pd[p];
    const __half2* ua = uv + (size_t)a * 32 + j0;       // u[a][16 ch]
    const __half2* vb = uv + (size_t)b * 32 + 16 + j0;  // v[b][16 ch]
    float r = 0.f;
    #pragma unroll
    for (int q = 0; q < 8; q++) {
        float2 uu = __half22float2(ua[q]);
        float2 vv = __half22float2(vb[q]);
        float2 bb = *(const float2*)(bm1 + half * 16 + q * 2);
        float2 ww = *(const float2*)(Wm2 + half * 16 + q * 2);
        float h0 = uu.x + vv.x + bb.x; h0 = h0 > 0.f ? h0 : 0.f; r = fmaf(h0, ww.x, r);
        float h1 = uu.y + vv.y + bb.y; h1 = h1 > 0.f ? h1 : 0.f; r = fmaf(h1, ww.y, r);
    }
    r += __shfl_xor(r, 1);
    if (half == 0) out[p] = r + bm2[0];
}

extern "C" void kernel_launch(void* const* d_in, const int* in_sizes, int n_in,
                              void* d_out, int out_size, void* d_ws, size_t ws_size,
                              hipStream_t stream)
{
    const float* x    = (const float*)d_in[0];
    const int*   ei   = (const int*)  d_in[1];
    const int*   ep   = (const int*)  d_in[2];
    const float* W1   = (const float*)d_in[3];
    const float* atS1 = (const float*)d_in[4];
    const float* atD1 = (const float*)d_in[5];
    const float* b1   = (const float*)d_in[6];
    const float* W2   = (const float*)d_in[7];
    const float* atS2 = (const float*)d_in[8];
    const float* atD2 = (const float*)d_in[9];
    const float* b2   = (const float*)d_in[10];
    const float* Wm1  = (const float*)d_in[11];
    const float* bm1  = (const float*)d_in[12];
    const float* Wm2  = (const float*)d_in[13];
    const float* bm2  = (const float*)d_in[14];
    float* out = (float*)d_out;

    int N = in_sizes[0] / 128;
    int E = in_sizes[1] / 2;
    int P = in_sizes[2] / 2;
    int Etot = E + N;

    // workspace carve (256B aligned)
    char* w = (char*)d_ws;
    auto alloc = [&](size_t bytes) {
        char* p = w; w += (bytes + 255) & ~(size_t)255; return p;
    };
    float*  W1T  = (float*)alloc(16384 * 4);
    float*  W2T  = (float*)alloc(8192 * 4);
    float*  Wm1T = (float*)alloc(4096 * 4);
    __half* h1   = (__half*)alloc((size_t)N * 128 * 2);  // fp16 gather table
    float*  x2   = (float*)alloc((size_t)N * 128 * 4);
    __half* h2   = (__half*)alloc((size_t)N * 64 * 2);   // fp16 gather table
    float*  hf   = (float*)alloc((size_t)N * 64 * 4);
    int*    rowp = (int*)alloc((size_t)(N + 1) * 4);
    int*    btot = (int*)alloc(64 * 4);
    int*    csrs = (int*)alloc((size_t)Etot * 4);
    // ---- contiguous zero-block (single memset) ----
    char* z0 = w;
    int*   deg  = (int*)alloc((size_t)N * 4);
    int*   curs = (int*)alloc((size_t)N * 4);
    char* z1 = w;
    float* as1  = (float*)alloc((size_t)N * 4 * 4);
    float* ad1  = (float*)alloc((size_t)N * 4 * 4);
    float* as2  = (float*)alloc((size_t)N * 4);
    float* ad2  = (float*)alloc((size_t)N * 4);
    __half* uv = (__half*)alloc((size_t)N * 64 * 2);     // fp16 gather table

    (void)hipMemsetAsync(z0, 0, (size_t)(z1 - z0), stream);

    prep_kernel<<<112, 256, 0, stream>>>(W1, W2, Wm1, W1T, W2T, Wm1T);

    int EN = E + N;
    hist_kernel<<<(EN + 255) / 256, 256, 0, stream>>>(ei + E, E, N, deg);
    int nb = (N + 1023) / 1024;
    scan1_kernel<<<nb, 1024, 0, stream>>>(deg, rowp, btot, N);
    scan2_kernel<<<1, 64, 0, stream>>>(btot, nb);
    scan3_kernel<<<nb, 1024, 0, stream>>>(rowp, btot, N);
    scatter_kernel<<<(EN + 255) / 256, 256, 0, stream>>>(ei, ei + E, E, N, rowp, curs, csrs);

    dim3 g1((N + 63) / 64, 2);
    gemm_att_kernel<<<g1, 256, 0, stream>>>(x, W1T, atS1, atD1, h1, as1, ad1,
                                            N, 128, 4, 5);
    edge1_kernel<<<(N + 3) / 4, 256, 0, stream>>>(csrs, rowp, (const __half2*)h1,
                                                  as1, ad1, b1, x2, N);
    dim3 g2((N + 63) / 64, 1);
    gemm_att_kernel<<<g2, 256, 0, stream>>>(x2, W2T, atS2, atD2, h2, as2, ad2,
                                            N, 64, 1, 6);
    edge2_kernel<<<(N + 3) / 4, 256, 0, stream>>>(csrs, rowp, h2, as2, ad2,
                                                  b2, hf, N);

    node_mlp_kernel<<<1024, 256, 0, stream>>>(hf, Wm1T, uv, N);
    pair_mlp_kernel<<<(2 * P + 255) / 256, 256, 0, stream>>>(ep, ep + P,
                                                             (const __half2*)uv,
                                                             bm1, Wm2, bm2, out, P);
}

// Round 9
// 251.696 us; speedup vs baseline: 1.1896x; 1.1094x over previous
//
#include <hip/hip_runtime.h>
#include <hip/hip_bf16.h>
#include <hip/hip_fp16.h>

// ---------------------------------------------------------------------------
// GAT link predictor: 2x GATConv + pair MLP.
// R9: MFMA f16 GEMMs (v_mfma_f32_16x16x32_f16, fp32 accum; A from global with
//     in-register cvt for L1, fp16 x2 for L2; B frags preloaded; LDS-staged
//     coalesced fp16 C store; fp32 shfl-reduced attention scores).
//     edge1: R8 32-slot staged gathers. edge2: R7 16-slot (R8 variant was
//     scratch-bound). fp16 gather tables, factorized MLP.
// ---------------------------------------------------------------------------

#define LRELU_SLOPE 0.2f

typedef _Float16 v8h __attribute__((ext_vector_type(8)));
typedef float    v4f __attribute__((ext_vector_type(4)));

// ---- weight prep: W1T/W2T transposed to [col][k] fp16; Wm1T fp32 ----
__global__ void __launch_bounds__(256) prep_kernel(
    const float* __restrict__ W1, const float* __restrict__ W2,
    const float* __restrict__ Wm1,
    _Float16* __restrict__ W1Th, _Float16* __restrict__ W2Th,
    float* __restrict__ Wm1T)
{
    int i = blockIdx.x * 256 + threadIdx.x;
    if (i < 16384) {                       // W1 [128][128] -> W1Th [128][128]
        int k = i >> 7, j = i & 127;
        W1Th[j * 128 + k] = (_Float16)W1[i];
    } else if (i < 16384 + 8192) {         // W2 [128][64] -> W2Th [64][128]
        int t = i - 16384;
        int k = t >> 6, j = t & 63;
        W2Th[j * 128 + k] = (_Float16)W2[t];
    } else if (i < 16384 + 8192 + 4096) {  // Wm1 [128][32] -> Wm1T [32][128]
        int t = i - 24576;
        int k = t >> 5, j = t & 31;
        Wm1T[j * 128 + k] = Wm1[t];
    }
}

// ---- CSR build ----
__global__ void __launch_bounds__(256) hist_kernel(
    const int* __restrict__ dst, int E, int N, int* __restrict__ deg)
{
    int i = blockIdx.x * 256 + threadIdx.x;
    if (i >= E + N) return;
    int d = (i < E) ? dst[i] : (i - E);
    atomicAdd(deg + d, 1);
}

__global__ void __launch_bounds__(1024) scan1_kernel(
    const int* __restrict__ deg, int* __restrict__ rowp,
    int* __restrict__ btot, int n)
{
    __shared__ int wsum[16];
    int t = threadIdx.x, lane = t & 63, wid = t >> 6;
    int idx = blockIdx.x * 1024 + t;
    int v = (idx < n) ? deg[idx] : 0;
    #pragma unroll
    for (int off = 1; off < 64; off <<= 1) {
        int y = __shfl_up(v, off);
        if (lane >= off) v += y;
    }
    if (lane == 63) wsum[wid] = v;
    __syncthreads();
    if (wid == 0) {
        int s = (lane < 16) ? wsum[lane] : 0;
        #pragma unroll
        for (int off = 1; off < 16; off <<= 1) {
            int y = __shfl_up(s, off);
            if (lane >= off) s += y;
        }
        if (lane < 16) wsum[lane] = s;
    }
    __syncthreads();
    if (wid > 0) v += wsum[wid - 1];
    if (idx < n) rowp[idx + 1] = v;
    if (t == 1023) btot[blockIdx.x] = v;
    if (idx == 0) rowp[0] = 0;
}

__global__ void __launch_bounds__(64) scan2_kernel(int* __restrict__ btot, int nb)
{
    int lane = threadIdx.x;
    int v = (lane < nb) ? btot[lane] : 0;
    #pragma unroll
    for (int off = 1; off < 64; off <<= 1) {
        int y = __shfl_up(v, off);
        if (lane >= off) v += y;
    }
    if (lane < nb) btot[lane] = v;
}

__global__ void __launch_bounds__(1024) scan3_kernel(
    int* __restrict__ rowp, const int* __restrict__ btot, int n)
{
    if (blockIdx.x == 0) return;
    int idx = blockIdx.x * 1024 + threadIdx.x;
    if (idx < n) rowp[idx + 1] += btot[blockIdx.x - 1];
}

__global__ void __launch_bounds__(256) scatter_kernel(
    const int* __restrict__ src, const int* __restrict__ dst, int E, int N,
    const int* __restrict__ rowptr, int* __restrict__ cursor,
    int* __restrict__ csrs)
{
    int i = blockIdx.x * 256 + threadIdx.x;
    if (i >= E + N) return;
    int s, d;
    if (i < E) { s = src[i]; d = dst[i]; } else { s = d = i - E; }
    int pos = rowptr[d] + atomicAdd(cursor + d, 1);
    csrs[pos] = s;
}

// ---- MFMA f16 GEMM + fused attention scores; OUT fp16 ----
// Block 256 thr = 4 waves; block tile 64 rows x 64 cols; wave = 16 rows.
// A frag: row=lane&15, k=(lane>>4)*8+j (8 contig). B frag: col=lane&15, same k.
// C/D: col=lane&15, row=(lane>>4)*4+reg. B (16 frags) preloaded in regs.
// AHALF=0: A fp32, cvt in-register. AHALF=1: A fp16 direct.
template<int AHALF>
__global__ void __launch_bounds__(256) gemm_att_kernel(
    const void* __restrict__ Xv, const _Float16* __restrict__ WTH,
    const float* __restrict__ atts, const float* __restrict__ attd,
    _Float16* __restrict__ OUT, float* __restrict__ oas, float* __restrict__ oad,
    int N, int ncols, int H, int headShift)
{
    __shared__ _Float16 cs[64 * 68];
    int tid = threadIdx.x;
    int lane = tid & 63;
    int wv = tid >> 6;
    int rowBase = blockIdx.x * 64 + wv * 16;
    int colBase = blockIdx.y * 64;
    int lr = lane & 15;       // frag row (A) / col (B,C)
    int lk = lane >> 4;       // k-group / C row-group

    // preload B fragments: 4 col-tiles x 4 k-steps
    v8h bf[4][4];
    #pragma unroll
    for (int ct = 0; ct < 4; ct++) {
        const _Float16* bp = WTH + (size_t)(colBase + ct * 16 + lr) * 128 + lk * 8;
        #pragma unroll
        for (int ks = 0; ks < 4; ks++)
            bf[ct][ks] = *(const v8h*)(bp + ks * 32);
    }

    int arow = rowBase + lr;
    if (arow >= N) arow = N - 1;            // clamp; stores masked below
    v4f acc[4];
    #pragma unroll
    for (int ct = 0; ct < 4; ct++) acc[ct] = (v4f){0.f, 0.f, 0.f, 0.f};

    if (AHALF) {
        const _Float16* ap = (const _Float16*)Xv + (size_t)arow * 128 + lk * 8;
        #pragma unroll
        for (int ks = 0; ks < 4; ks++) {
            v8h af = *(const v8h*)(ap + ks * 32);
            #pragma unroll
            for (int ct = 0; ct < 4; ct++)
                acc[ct] = __builtin_amdgcn_mfma_f32_16x16x32_f16(af, bf[ct][ks],
                                                                 acc[ct], 0, 0, 0);
        }
    } else {
        const float* ap = (const float*)Xv + (size_t)arow * 128 + lk * 8;
        #pragma unroll
        for (int ks = 0; ks < 4; ks++) {
            float4 a0 = *(const float4*)(ap + ks * 32);
            float4 a1 = *(const float4*)(ap + ks * 32 + 4);
            v8h af;
            af[0] = (_Float16)a0.x; af[1] = (_Float16)a0.y;
            af[2] = (_Float16)a0.z; af[3] = (_Float16)a0.w;
            af[4] = (_Float16)a1.x; af[5] = (_Float16)a1.y;
            af[6] = (_Float16)a1.z; af[7] = (_Float16)a1.w;
            #pragma unroll
            for (int ct = 0; ct < 4; ct++)
                acc[ct] = __builtin_amdgcn_mfma_f32_16x16x32_f16(af, bf[ct][ks],
                                                                 acc[ct], 0, 0, 0);
        }
    }

    // ---- attention scores (fp32, shfl-reduce over the 16 col lanes) ----
    int ctPerHead = (1 << headShift) >> 4;        // 2 (L1) or 4 (L2)
    #pragma unroll
    for (int hh = 0; hh < 2; hh++) {
        if (hh * ctPerHead >= 4) break;
        float ps[4] = {0.f, 0.f, 0.f, 0.f};
        float pd[4] = {0.f, 0.f, 0.f, 0.f};
        for (int c2 = 0; c2 < ctPerHead; c2++) {
            int ct = hh * ctPerHead + c2;
            int col = colBase + ct * 16 + lr;
            float ws = atts[col], wd = attd[col];
            #pragma unroll
            for (int r = 0; r < 4; r++) {
                ps[r] = fmaf(acc[ct][r], ws, ps[r]);
                pd[r] = fmaf(acc[ct][r], wd, pd[r]);
            }
        }
        #pragma unroll
        for (int r = 0; r < 4; r++) {
            #pragma unroll
            for (int m = 1; m < 16; m <<= 1) {
                ps[r] += __shfl_xor(ps[r], m);
                pd[r] += __shfl_xor(pd[r], m);
            }
        }
        if (lr == 0) {
            int head = (colBase >> headShift) + hh;
            #pragma unroll
            for (int r = 0; r < 4; r++) {
                int row = rowBase + lk * 4 + r;
                if (row < N) {
                    oas[(size_t)row * H + head] = ps[r];
                    oad[(size_t)row * H + head] = pd[r];
                }
            }
        }
    }

    // ---- C to LDS (fp16), then coalesced 32B stores ----
    #pragma unroll
    for (int ct = 0; ct < 4; ct++)
        #pragma unroll
        for (int r = 0; r < 4; r++)
            cs[(wv * 16 + lk * 4 + r) * 68 + ct * 16 + lr] = (_Float16)acc[ct][r];
    __syncthreads();
    int rr = tid >> 2;                     // 0..63 block-local row
    int cb = (tid & 3) * 16;               // col offset (halfs)
    int grow = blockIdx.x * 64 + rr;
    if (grow < N) {
        const uint4* sp = (const uint4*)(cs + rr * 68 + cb);
        _Float16* op = OUT + (size_t)grow * ncols + colBase + cb;
        uint4 w0 = sp[0];
        uint4 w1 = sp[1];
        *(uint4*)op = w0;
        *(uint4*)(op + 8) = w1;
    }
}

// ---- layer-1 edge pass: one wave per node; 32-slot staged gathers ----
__global__ void __launch_bounds__(256) edge1_kernel(
    const int* __restrict__ csr, const int* __restrict__ rowp,
    const __half2* __restrict__ h1, const float* __restrict__ as1,
    const float* __restrict__ ad1, const float* __restrict__ b1,
    __half* __restrict__ x2h, int N)
{
    int lane = threadIdx.x & 63;
    int n = __builtin_amdgcn_readfirstlane(blockIdx.x * 4 + (threadIdx.x >> 6));
    if (n >= N) return;
    int rs = rowp[n], re = rowp[n + 1];
    int hd = lane >> 4;
    int el = lane >> 2, hh = lane & 3;
    float adv = ad1[n * 4 + hh];
    float accx = 0.f, accy = 0.f, srun = 0.f;
    for (int base = rs; base < re; base += 32) {
        int cnt = re - base; if (cnt > 32) cnt = 32;
        float wvA = 0.f, wvB = 0.f;
        if (el < cnt) {
            int s = csr[base + el];
            float e = as1[s * 4 + hh] + adv;
            e = e > 0.f ? e : LRELU_SLOPE * e;
            wvA = __expf(e);
        }
        if (el + 16 < cnt) {
            int s = csr[base + 16 + el];
            float e = as1[s * 4 + hh] + adv;
            e = e > 0.f ? e : LRELU_SLOPE * e;
            wvB = __expf(e);
        }
        float t = wvA + wvB;
        t += __shfl_xor(t, 4);  t += __shfl_xor(t, 8);
        t += __shfl_xor(t, 16); t += __shfl_xor(t, 32);
        srun += t;
        __half2 hv[32];
        #pragma unroll
        for (int e2 = 0; e2 < 32; ++e2) {
            int ee = e2 < cnt ? e2 : cnt - 1;      // wave-uniform clamp
            int s = csr[base + ee];                // uniform -> s_load
            hv[e2] = h1[(size_t)s * 64 + lane];
        }
        #pragma unroll
        for (int e2 = 0; e2 < 32; ++e2) {
            float av = (e2 < 16) ? __shfl(wvA, (e2 << 2) | hd)
                                 : __shfl(wvB, ((e2 - 16) << 2) | hd);
            float2 v = __half22float2(hv[e2]);
            accx = fmaf(av, v.x, accx);
            accy = fmaf(av, v.y, accy);
        }
    }
    float sden = __shfl(srun, hd) + 1e-16f;
    float inv = 1.f / sden;
    float2 bv = *(const float2*)(b1 + lane * 2);
    float o0 = accx * inv + bv.x;
    float o1 = accy * inv + bv.y;
    o0 = o0 > 0.f ? o0 : (__expf(o0) - 1.f);   // ELU
    o1 = o1 > 0.f ? o1 : (__expf(o1) - 1.f);
    *(__half2*)(x2h + (size_t)n * 128 + lane * 2) = __floats2half2_rn(o0, o1);
}

// ---- layer-2 edge pass (1 head, 64 channels; lane = channel), 16-slot ----
__global__ void __launch_bounds__(256) edge2_kernel(
    const int* __restrict__ csr, const int* __restrict__ rowp,
    const __half* __restrict__ h2, const float* __restrict__ as2,
    const float* __restrict__ ad2, const float* __restrict__ b2,
    float* __restrict__ hf, int N)
{
    int lane = threadIdx.x & 63;
    int n = __builtin_amdgcn_readfirstlane(blockIdx.x * 4 + (threadIdx.x >> 6));
    if (n >= N) return;
    int rs = rowp[n], re = rowp[n + 1];
    float adv = ad2[n];
    float acc = 0.f, srun = 0.f;
    for (int base = rs; base < re; base += 16) {
        int cnt = re - base; if (cnt > 16) cnt = 16;
        float wv = 0.f;
        if (lane < cnt) {
            int s = csr[base + lane];
            float e = as2[s] + adv;
            e = e > 0.f ? e : LRELU_SLOPE * e;
            wv = __expf(e);
        }
        srun += wv;
        if (cnt == 16) {
            #pragma unroll
            for (int e2 = 0; e2 < 16; ++e2) {
                int s = csr[base + e2];                    // uniform -> s_load
                float av = __shfl(wv, e2);
                acc = fmaf(av, __half2float(h2[(size_t)s * 64 + lane]), acc);
            }
        } else {
            for (int e2 = 0; e2 < cnt; ++e2) {
                int s = csr[base + e2];
                float av = __shfl(wv, e2);
                acc = fmaf(av, __half2float(h2[(size_t)s * 64 + lane]), acc);
            }
        }
    }
    #pragma unroll
    for (int m = 1; m < 64; m <<= 1) srun += __shfl_xor(srun, m);
    float o = acc / (srun + 1e-16f) + b2[lane];
    hf[(size_t)n * 64 + lane] = o;
}

// ---- per-node MLP projections: u|v = hf[n] @ Wm1 halves; uv fp16 ----
__global__ void __launch_bounds__(256) node_mlp_kernel(
    const float* __restrict__ hf, const float* __restrict__ Wm1T,
    __half* __restrict__ uv, int N)
{
    int lane = threadIdx.x & 63;
    int j = lane & 31, half = lane >> 5;
    const float* wr = Wm1T + j * 128 + half * 64;
    float wreg[64];
    #pragma unroll
    for (int q = 0; q < 16; q++) {
        float4 t = ((const float4*)wr)[q];
        wreg[q*4] = t.x; wreg[q*4+1] = t.y; wreg[q*4+2] = t.z; wreg[q*4+3] = t.w;
    }
    int wgid = __builtin_amdgcn_readfirstlane(blockIdx.x * 4 + (threadIdx.x >> 6));
    int nwaves = gridDim.x * 4;
    for (int n = wgid; n < N; n += nwaves) {
        const float* hr = hf + (size_t)n * 64;
        float acc = 0.f;
        #pragma unroll
        for (int k = 0; k < 64; k += 4) {
            float4 hv = *(const float4*)(hr + k);   // uniform across wave
            acc = fmaf(hv.x, wreg[k],   acc);
            acc = fmaf(hv.y, wreg[k+1], acc);
            acc = fmaf(hv.z, wreg[k+2], acc);
            acc = fmaf(hv.w, wreg[k+3], acc);
        }
        uv[(size_t)n * 64 + lane] = __float2half_rn(acc);
    }
}

// ---- pair MLP: 2 lanes per pair (16 hidden units each), shfl-reduce ----
__global__ void __launch_bounds__(256) pair_mlp_kernel(
    const int* __restrict__ ps, const int* __restrict__ pd,
    const __half2* __restrict__ uv, const float* __restrict__ bm1,
    const float* __restrict__ Wm2, const float* __restrict__ bm2,
    float* __restrict__ out, int P)
{
    int gid = blockIdx.x * 256 + threadIdx.x;
    int p = gid >> 1;
    if (p >= P) return;
    int half = gid & 1;
    int j0 = half * 8;
    int a = ps[p], b = pd[p];
    const __half2* ua = uv + (size_t)a * 32 + j0;
    const __half2* vb = uv + (size_t)b * 32 + 16 + j0;
    float r = 0.f;
    #pragma unroll
    for (int q = 0; q < 8; q++) {
        float2 uu = __half22float2(ua[q]);
        float2 vv = __half22float2(vb[q]);
        float2 bb = *(const float2*)(bm1 + half * 16 + q * 2);
        float2 ww = *(const float2*)(Wm2 + half * 16 + q * 2);
        float h0 = uu.x + vv.x + bb.x; h0 = h0 > 0.f ? h0 : 0.f; r = fmaf(h0, ww.x, r);
        float h1 = uu.y + vv.y + bb.y; h1 = h1 > 0.f ? h1 : 0.f; r = fmaf(h1, ww.y, r);
    }
    r += __shfl_xor(r, 1);
    if (half == 0) out[p] = r + bm2[0];
}

extern "C" void kernel_launch(void* const* d_in, const int* in_sizes, int n_in,
                              void* d_out, int out_size, void* d_ws, size_t ws_size,
                              hipStream_t stream)
{
    const float* x    = (const float*)d_in[0];
    const int*   ei   = (const int*)  d_in[1];
    const int*   ep   = (const int*)  d_in[2];
    const float* W1   = (const float*)d_in[3];
    const float* atS1 = (const float*)d_in[4];
    const float* atD1 = (const float*)d_in[5];
    const float* b1   = (const float*)d_in[6];
    const float* W2   = (const float*)d_in[7];
    const float* atS2 = (const float*)d_in[8];
    const float* atD2 = (const float*)d_in[9];
    const float* b2   = (const float*)d_in[10];
    const float* Wm1  = (const float*)d_in[11];
    const float* bm1  = (const float*)d_in[12];
    const float* Wm2  = (const float*)d_in[13];
    const float* bm2  = (const float*)d_in[14];
    float* out = (float*)d_out;

    int N = in_sizes[0] / 128;
    int E = in_sizes[1] / 2;
    int P = in_sizes[2] / 2;
    int Etot = E + N;

    // workspace carve (256B aligned)
    char* w = (char*)d_ws;
    auto alloc = [&](size_t bytes) {
        char* p = w; w += (bytes + 255) & ~(size_t)255; return p;
    };
    _Float16* W1Th = (_Float16*)alloc(16384 * 2);
    _Float16* W2Th = (_Float16*)alloc(8192 * 2);
    float*    Wm1T = (float*)alloc(4096 * 4);
    _Float16* h1   = (_Float16*)alloc((size_t)N * 128 * 2);  // fp16
    __half*   x2h  = (__half*)alloc((size_t)N * 128 * 2);    // fp16
    _Float16* h2   = (_Float16*)alloc((size_t)N * 64 * 2);   // fp16
    float*    hf   = (float*)alloc((size_t)N * 64 * 4);
    int*      rowp = (int*)alloc((size_t)(N + 1) * 4);
    int*      btot = (int*)alloc(64 * 4);
    int*      csrs = (int*)alloc((size_t)Etot * 4);
    // ---- contiguous zero-block (single memset) ----
    char* z0 = w;
    int*   deg  = (int*)alloc((size_t)N * 4);
    int*   curs = (int*)alloc((size_t)N * 4);
    char* z1 = w;
    float* as1  = (float*)alloc((size_t)N * 4 * 4);
    float* ad1  = (float*)alloc((size_t)N * 4 * 4);
    float* as2  = (float*)alloc((size_t)N * 4);
    float* ad2  = (float*)alloc((size_t)N * 4);
    __half* uv = (__half*)alloc((size_t)N * 64 * 2);

    (void)hipMemsetAsync(z0, 0, (size_t)(z1 - z0), stream);

    prep_kernel<<<112, 256, 0, stream>>>(W1, W2, Wm1, W1Th, W2Th, Wm1T);

    int EN = E + N;
    hist_kernel<<<(EN + 255) / 256, 256, 0, stream>>>(ei + E, E, N, deg);
    int nb = (N + 1023) / 1024;
    scan1_kernel<<<nb, 1024, 0, stream>>>(deg, rowp, btot, N);
    scan2_kernel<<<1, 64, 0, stream>>>(btot, nb);
    scan3_kernel<<<nb, 1024, 0, stream>>>(rowp, btot, N);
    scatter_kernel<<<(EN + 255) / 256, 256, 0, stream>>>(ei, ei + E, E, N, rowp, curs, csrs);

    dim3 g1((N + 63) / 64, 2);
    gemm_att_kernel<0><<<g1, 256, 0, stream>>>(x, W1Th, atS1, atD1, h1,
                                               as1, ad1, N, 128, 4, 5);
    edge1_kernel<<<(N + 3) / 4, 256, 0, stream>>>(csrs, rowp, (const __half2*)h1,
                                                  as1, ad1, b1, x2h, N);
    dim3 g2((N + 63) / 64, 1);
    gemm_att_kernel<1><<<g2, 256, 0, stream>>>(x2h, W2Th, atS2, atD2, h2,
                                               as2, ad2, N, 64, 1, 6);
    edge2_kernel<<<(N + 3) / 4, 256, 0, stream>>>(csrs, rowp, (const __half*)h2,
                                                  as2, ad2, b2, hf, N);

    node_mlp_kernel<<<1024, 256, 0, stream>>>(hf, Wm1T, uv, N);
    pair_mlp_kernel<<<(2 * P + 255) / 256, 256, 0, stream>>>(ep, ep + P,
                                                             (const __half2*)uv,
                                                             bm1, Wm2, bm2, out, P);
}